// Round 18
// baseline (1460.138 us; speedup 1.0000x reference)
//
#include <hip/hip_runtime.h>
#include <math.h>

#define NENT 20000
#define HD 256
#define TT 8
#define EE 100000
#define MM 150000
#define NR2 500
#define NR2P 512        /* padded rows */
#define GDIM 768
#define SLOPE 0.2291666666666667f
#define NAGG_BLK 2500

typedef short v8s __attribute__((ext_vector_type(8)));
typedef float v4f __attribute__((ext_vector_type(4)));

__device__ __forceinline__ float sigmoidf_(float x){ return 1.0f/(1.0f+expf(-x)); }
__device__ __forceinline__ unsigned short f2bf(float x){
  unsigned u = __float_as_uint(x);
  return (unsigned short)((u + 0x7FFFu + ((u>>16)&1u)) >> 16);
}
__device__ __forceinline__ unsigned pack2bf(float lo, float hi){
  return ((unsigned)f2bf(lo)) | (((unsigned)f2bf(hi))<<16);
}
__device__ __forceinline__ float bfl(unsigned u){ return __uint_as_float(u<<16); }
__device__ __forceinline__ float bfh(unsigned u){ return __uint_as_float(u & 0xffff0000u); }

__device__ __forceinline__ float block_sum_256(float v){
  #pragma unroll
  for(int o=32;o>0;o>>=1) v += __shfl_down(v,o,64);
  __shared__ float wsum[4];
  __shared__ float tot;
  int lane = threadIdx.x & 63, wid = threadIdx.x >> 6;
  if(lane==0) wsum[wid]=v;
  __syncthreads();
  if(threadIdx.x==0) tot = wsum[0]+wsum[1]+wsum[2]+wsum[3];
  __syncthreads();
  return tot;
}

// ---------------- setup kernels ----------------

__global__ __launch_bounds__(256) void k_l2norm_clear(const float* __restrict__ in,
                                                      float* __restrict__ out,
                                                      unsigned short* __restrict__ outbf,
                                                      int* __restrict__ deg,
                                                      int* __restrict__ cursor){
  int r=blockIdx.x, j=threadIdx.x;
  size_t idx=(size_t)r*HD+j;
  float v = in[idx];
  float ss = block_sum_256(v*v);
  float o = v / fmaxf(sqrtf(ss), 1e-12f);
  out[idx] = o;
  outbf[idx] = f2bf(o);
  for(int i=blockIdx.x*256+threadIdx.x; i<TT*NENT; i+=gridDim.x*256){
    deg[i]=0; cursor[i]=0;
  }
}

// weight prep + degree count + pad-zeroing.
// Bfrag:  v8s idx=(kblk*32+frag)*64+lane -> B^T[frag*16+(lane&15)][kblk*32+(lane>>4)*8..]
// GRU frags (K=256 -> 8 kblks; 48 n-frags over 768 cols): v8s idx=(kblk*48+f)*64+lane
//   WtBfr: B[n][k]=W_ih[n][256+k] (k<256);  Whhfr: B[n][k]=W_hh[n][k]
// Wnp: [kp][256] u32 pack(Wn[2kp][col],Wn[2kp+1][col])
__global__ __launch_bounds__(256) void k_prep(const float* __restrict__ W_ih,
                                              const float* __restrict__ W_hh,
                                              const float* __restrict__ Wn,
                                              const float* __restrict__ Wl,
                                              const float* __restrict__ Wtg,
                                              const float* __restrict__ emb_rel,
                                              const int* __restrict__ dst,
                                              float* __restrict__ WtA,
                                              unsigned* __restrict__ WtBfr,
                                              unsigned* __restrict__ Whhfr,
                                              unsigned* __restrict__ Bfrag_u,
                                              unsigned* __restrict__ Wnp,
                                              float* __restrict__ h0,
                                              unsigned short* __restrict__ h0bf,
                                              unsigned* __restrict__ xmbf,
                                              float* __restrict__ gi_const_pad,
                                              int* __restrict__ deg){
  int id0=blockIdx.x*256+threadIdx.x;
  int stride=gridDim.x*256;
  for(int id=id0; id<256*GDIM; id+=stride){
    int k=id/GDIM, n=id%GDIM;
    WtA[id]=W_ih[(size_t)n*512+k];
  }
  // GRU fragment layouts: 8 kblks * 48 f * 64 lanes * 4 u32 = 98304 u32 each
  for(int id=id0; id<98304; id+=stride){
    int vidx=id>>2, j=id&3;
    int lane=vidx&63;
    int f=(vidx>>6)%48;
    int kblk=vidx/(48*64);           // 0..7  (K=256)
    int n=f*16+(lane&15);
    int k=kblk*32+(lane>>4)*8+2*j;   // 0..254
    WtBfr[id]=pack2bf(W_ih[(size_t)n*512+256+k], W_ih[(size_t)n*512+256+k+1]);
    Whhfr[id]=pack2bf(W_hh[(size_t)n*256+k],     W_hh[(size_t)n*256+k+1]);
  }
  for(int id=id0; id<131072; id+=stride){
    int vidx = id>>2, j = id&3;
    int lane = vidx&63, frag = (vidx>>6)&31, kblk = vidx>>11;
    int nr = frag*16 + (lane&15);
    int k  = kblk*32 + (lane>>4)*8 + 2*j;
    float lo, hi;
    if(nr < HD){
      lo = (k<HD)?     Wn[(size_t)k*HD+nr]      : Wl[(size_t)(k-HD)*HD+nr];
      hi = (k+1<HD)?   Wn[(size_t)(k+1)*HD+nr]  : Wl[(size_t)(k+1-HD)*HD+nr];
    } else {
      lo = (k<HD)?   0.f : Wtg[(size_t)(k-HD)*HD+(nr-HD)];
      hi = (k+1<HD)? 0.f : Wtg[(size_t)(k+1-HD)*HD+(nr-HD)];
    }
    Bfrag_u[id]=pack2bf(lo,hi);
  }
  for(int id=id0; id<128*256; id+=stride){
    int kp=id>>8, col=id&255;
    Wnp[id]=pack2bf(Wn[(size_t)(2*kp)*HD+col], Wn[(size_t)(2*kp+1)*HD+col]);
  }
  for(int id=id0; id<NR2*HD; id+=stride){ h0[id]=emb_rel[id]; h0bf[id]=f2bf(emb_rel[id]); }
  for(int id=id0; id<12*HD; id+=stride){ h0[NR2*HD+id]=0.f; h0bf[NR2*HD+id]=0; }
  for(int id=id0; id<12*128; id+=stride) xmbf[NR2*128+id]=0;
  for(int id=id0; id<12*GDIM; id+=stride) gi_const_pad[(size_t)NR2*GDIM+id]=0.f;
  for(int id=id0; id<TT*EE; id+=stride){
    int t=id/EE, e=id-t*EE;
    atomicAdd(&deg[t*NENT + dst[(size_t)t*EE+e]], 1);
  }
}

// role-split: blocks [0,TT) per-timestep scan; blocks [TT,TT+96) gi_const GEMM
__global__ __launch_bounds__(256) void k_scangemm(const int* __restrict__ deg_all,
                                                  int* __restrict__ offs_all,
                                                  const float* __restrict__ A,
                                                  const float* __restrict__ B,
                                                  const float* __restrict__ bias,
                                                  float* __restrict__ C){
  int tid=threadIdx.x;
  if(blockIdx.x < TT){
    int t=blockIdx.x;
    const int* deg=deg_all+t*NENT;
    int* offs=offs_all+t*(NENT+1);
    __shared__ int part[256];
    const int per=(NENT+255)>>8;
    int base=tid*per;
    int s=0;
    for(int i=0;i<per;i++){ int idx=base+i; if(idx<NENT) s+=deg[idx]; }
    part[tid]=s;
    __syncthreads();
    for(int off=1; off<256; off<<=1){
      int v=(tid>=off)? part[tid-off]:0;
      __syncthreads();
      part[tid]+=v;
      __syncthreads();
    }
    int run=part[tid]-s;
    for(int i=0;i<per;i++){ int idx=base+i; if(idx<NENT){ offs[idx]=run; run+=deg[idx]; } }
    if(tid==255) offs[NENT]=part[255];
    return;
  }
  int tile=blockIdx.x-TT;
  int n0=(tile%12)*64, m0=(tile/12)*64;
  __shared__ float As[16][64];
  __shared__ float Bs[16][64];
  int tx=tid&15, ty=tid>>4;
  float acc[4][4]={};
  for(int k0=0;k0<HD;k0+=16){
    int ml=tid>>2, kl=(tid&3)*4;
    float4 av=make_float4(0.f,0.f,0.f,0.f);
    if(m0+ml<NR2) av=*(const float4*)&A[(size_t)(m0+ml)*HD+k0+kl];
    As[kl+0][ml]=av.x; As[kl+1][ml]=av.y; As[kl+2][ml]=av.z; As[kl+3][ml]=av.w;
    int kb=tid>>4, nb=(tid&15)*4;
    float4 bv=*(const float4*)&B[(size_t)(k0+kb)*GDIM+n0+nb];
    *(float4*)&Bs[kb][nb]=bv;
    __syncthreads();
    #pragma unroll
    for(int kk=0;kk<16;kk++){
      float a0=As[kk][ty*4+0],a1=As[kk][ty*4+1],a2=As[kk][ty*4+2],a3=As[kk][ty*4+3];
      float b0=Bs[kk][tx*4+0],b1=Bs[kk][tx*4+1],b2=Bs[kk][tx*4+2],b3=Bs[kk][tx*4+3];
      acc[0][0]+=a0*b0; acc[0][1]+=a0*b1; acc[0][2]+=a0*b2; acc[0][3]+=a0*b3;
      acc[1][0]+=a1*b0; acc[1][1]+=a1*b1; acc[1][2]+=a1*b2; acc[1][3]+=a1*b3;
      acc[2][0]+=a2*b0; acc[2][1]+=a2*b1; acc[2][2]+=a2*b2; acc[2][3]+=a2*b3;
      acc[3][0]+=a3*b0; acc[3][1]+=a3*b1; acc[3][2]+=a3*b2; acc[3][3]+=a3*b3;
    }
    __syncthreads();
  }
  #pragma unroll
  for(int i=0;i<4;i++){
    int row=m0+ty*4+i;
    if(row>=NR2) continue;
    #pragma unroll
    for(int j=0;j<4;j++){
      int col=n0+tx*4+j;
      C[(size_t)row*GDIM+col]=acc[i][j]+bias[col];
    }
  }
}

__global__ __launch_bounds__(256) void k_scatter8(const int* __restrict__ dst,
                                                  const int* __restrict__ src,
                                                  const int* __restrict__ et,
                                                  const int* __restrict__ offs_all,
                                                  int* __restrict__ cursor,
                                                  int* __restrict__ ssrc,
                                                  int* __restrict__ setype){
  int id=blockIdx.x*256+threadIdx.x;
  if(id>=TT*EE) return;
  int t=id/EE, e=id-t*EE;
  size_t ge=(size_t)t*EE+e;
  int d=dst[ge];
  int p = offs_all[t*(NENT+1)+d] + atomicAdd(&cursor[t*NENT+d], 1);
  ssrc[(size_t)t*EE+p]=src[ge];
  setype[(size_t)t*EE+p]=et[ge];
}

// ---------------- per-step kernels ----------------

// D1: pure gathers. blocks [0,NR2): xmean -> xmbf (bf16); [NR2,NR2+NAGG_BLK): srcagg.
__global__ __launch_bounds__(256) void k_gath(
    const unsigned* __restrict__ Hbf_u,
    const int* __restrict__ ssrc,
    const int* __restrict__ offs,
    unsigned* __restrict__ aggsrc,
    const int* __restrict__ rte, const int* __restrict__ rrel,
    unsigned* __restrict__ xmbf)
{
  int bid=blockIdx.x, tid=threadIdx.x;
  int lane=tid&63, wid=tid>>6;

  if(bid >= NR2){
    int gw=(bid-NR2)*4+wid;
    const int nw=NAGG_BLK*4;
    for(int v=gw; v<NENT; v+=nw){
      int s0=offs[v], s1=offs[v+1];
      float l0=0.f,g0=0.f,l1=0.f,g1=0.f;
      float m0=0.f,n0=0.f,m1=0.f,n1=0.f;
      int e=s0;
      for(; e+1<s1; e+=2){
        int sv1=ssrc[e], sv2=ssrc[e+1];
        uint2 w1=*(const uint2*)&Hbf_u[(size_t)sv1*128 + 2*lane];
        uint2 w2=*(const uint2*)&Hbf_u[(size_t)sv2*128 + 2*lane];
        l0+=bfl(w1.x); g0+=bfh(w1.x);
        l1+=bfl(w1.y); g1+=bfh(w1.y);
        m0+=bfl(w2.x); n0+=bfh(w2.x);
        m1+=bfl(w2.y); n1+=bfh(w2.y);
      }
      if(e<s1){
        int sv=ssrc[e];
        uint2 w1=*(const uint2*)&Hbf_u[(size_t)sv*128 + 2*lane];
        l0+=bfl(w1.x); g0+=bfh(w1.x);
        l1+=bfl(w1.y); g1+=bfh(w1.y);
      }
      l0+=m0; g0+=n0; l1+=m1; g1+=n1;
      float inv=1.f/fmaxf((float)(s1-s0),1.f);
      uint2 o;
      o.x=pack2bf(l0*inv,g0*inv);
      o.y=pack2bf(l1*inv,g1*inv);
      *(uint2*)&aggsrc[(size_t)v*128 + 2*lane]=o;
    }
    return;
  }

  // ---- xmean for relation r ----
  int r=bid;
  __shared__ int buf[64];
  __shared__ float comb[128][2];
  int lo=0, hi=MM;
  while(lo<hi){ int mid=(lo+hi)>>1; if(rrel[mid]<r) lo=mid+1; else hi=mid; }
  int start=lo;
  lo=start; hi=MM;
  while(lo<hi){ int mid=(lo+hi)>>1; if(rrel[mid]<r+1) lo=mid+1; else hi=mid; }
  int end=lo;

  int half = tid>>7, cp = tid&127;
  float a0=0.f,a1=0.f,b0=0.f,b1=0.f;
  float c0=0.f,c1=0.f,d0=0.f,d1=0.f;
  for(int q0=start; q0<end; q0+=64){
    int cnt = min(64, end-q0);
    __syncthreads();
    if(tid<cnt) buf[tid]=rte[q0+tid];
    __syncthreads();
    int i = half;
    for(; i+6<cnt; i+=8){
      unsigned u1 = Hbf_u[(size_t)buf[i]*128 + cp];
      unsigned u2 = Hbf_u[(size_t)buf[i+2]*128 + cp];
      unsigned u3 = Hbf_u[(size_t)buf[i+4]*128 + cp];
      unsigned u4 = Hbf_u[(size_t)buf[i+6]*128 + cp];
      a0 += bfl(u1); a1 += bfh(u1);
      b0 += bfl(u2); b1 += bfh(u2);
      c0 += bfl(u3); c1 += bfh(u3);
      d0 += bfl(u4); d1 += bfh(u4);
    }
    for(; i<cnt; i+=2){
      unsigned u1 = Hbf_u[(size_t)buf[i]*128 + cp];
      a0 += bfl(u1); a1 += bfh(u1);
    }
  }
  a0+=b0+c0+d0; a1+=b1+c1+d1;
  if(half==1){ comb[cp][0]=a0; comb[cp][1]=a1; }
  __syncthreads();
  if(half==0){
    float d = fmaxf((float)(end-start), 1.f);
    xmbf[(size_t)r*128+cp]=pack2bf((a0+comb[cp][0])/d, (a1+comb[cp][1])/d);
  }
}

// D2: GRU via MFMA (K=256 -> 8 kblks). 32 blocks x 16 rows.
// Wave w owns col-triples {c,c+256,c+512}, c=(4w+j)*16+fr -> gate triples lane-local.
// LDS: xma bf16 [16][256] swz @0 (8KB) | h0a bf16 swz @8192 (8KB)
//      h0sn f32 [16][260] @16384 | rsum @33024
__global__ __launch_bounds__(256) void k_gru(
    const unsigned* __restrict__ xmbf,
    const unsigned* __restrict__ WtBfr,
    const unsigned* __restrict__ Whhfr,
    const unsigned* __restrict__ Wnp,
    const float* __restrict__ gic,
    const float* __restrict__ b_hh,
    float* h0,                     // rw (no restrict: aliased read+write)
    unsigned short* h0bf,          // rw
    float* __restrict__ HW)
{
  __shared__ __align__(16) char smem[33280];
  float* h0sn=(float*)(smem+16384);
  float (*rsum)[16]=(float(*)[16])(smem+33024);
  int tid=threadIdx.x, lane=tid&63, w=tid>>6;
  int fr=lane&15, fg=lane>>4;
  int blk16=blockIdx.x*16;

  const unsigned* h0bf_u=(const unsigned*)h0bf;
  #pragma unroll
  for(int q=0;q<8;q++){
    int idx=tid+q*256;
    int row=idx>>7, cu=idx&127;
    unsigned xv=xmbf[(size_t)(blk16+row)*128+cu];
    unsigned hv=h0bf_u[(size_t)(blk16+row)*128+cu];
    int byte=(row*512+cu*4)^((row&7)<<4);
    *(unsigned*)(smem+byte)=xv;
    *(unsigned*)(smem+8192+byte)=hv;
  }
  #pragma unroll
  for(int q=0;q<16;q++){
    int idx=tid+q*256;
    int row=idx>>8, c=idx&255;
    h0sn[row*260+c]=h0[(size_t)(blk16+row)*HD+c];
  }
  __syncthreads();

  // GEMMs over K=256 (8 kblks)
  v4f agi[12]={}, agh[12]={};
  #pragma unroll
  for(int kblk=0;kblk<8;kblk++){
    int abyte=(fr*512 + kblk*64 + fg*16)^((fr&7)<<4);
    v8s afx=*(const v8s*)(smem+abyte);
    v8s afh=*(const v8s*)(smem+8192+abyte);
    #pragma unroll
    for(int q=0;q<12;q++){
      int f=(q>>2)*16 + 4*w + (q&3);
      v8s bx=*(const v8s*)&WtBfr[((size_t)(kblk*48+f)*64+lane)*4];
      v8s bh=*(const v8s*)&Whhfr[((size_t)(kblk*48+f)*64+lane)*4];
      agi[q]=__builtin_amdgcn_mfma_f32_16x16x32_bf16(afx,bx,agi[q],0,0,0);
      agh[q]=__builtin_amdgcn_mfma_f32_16x16x32_bf16(afh,bh,agh[q],0,0,0);
    }
  }

  // gates + l2norm
  float hn[4][4];
  float ssum[4]={};
  #pragma unroll
  for(int j=0;j<4;j++){
    int c=(4*w+j)*16+fr;
    #pragma unroll
    for(int i=0;i<4;i++){
      int row16=fg*4+i;
      size_t gb=(size_t)(blk16+row16)*GDIM;
      float ir=agi[0+j][i]+gic[gb+c];
      float iz=agi[4+j][i]+gic[gb+256+c];
      float ig=agi[8+j][i]+gic[gb+512+c];
      float hr=agh[0+j][i]+b_hh[c];
      float hz=agh[4+j][i]+b_hh[256+c];
      float hg=agh[8+j][i]+b_hh[512+c];
      float rr=sigmoidf_(ir+hr), z=sigmoidf_(iz+hz);
      float g=tanhf(ig+rr*hg);
      float v=(1.f-z)*g + z*h0sn[row16*260+c];
      hn[j][i]=v;
      ssum[i]+=v*v;
    }
  }
  #pragma unroll
  for(int i=0;i<4;i++){
    float s=ssum[i];
    s+=__shfl_xor(s,1,64); s+=__shfl_xor(s,2,64);
    s+=__shfl_xor(s,4,64); s+=__shfl_xor(s,8,64);
    if(fr==0) rsum[w][fg*4+i]=s;
  }
  __syncthreads();
  #pragma unroll
  for(int i=0;i<4;i++){
    int row16=fg*4+i;
    int grow=blk16+row16;
    float tot=rsum[0][row16]+rsum[1][row16]+rsum[2][row16]+rsum[3][row16];
    float inv=1.f/fmaxf(sqrtf(tot),1e-12f);
    #pragma unroll
    for(int j=0;j<4;j++){
      int c=(4*w+j)*16+fr;
      float o=hn[j][i]*inv;
      h0sn[row16*260+c]=o;
      if(grow<NR2){
        h0[(size_t)grow*HD+c]=o;
        h0bf[(size_t)grow*HD+c]=f2bf(o);
      }
    }
  }
  __syncthreads();

  // HW = h0_new @ Wn
  float hw[16]={};
  #pragma unroll 4
  for(int kp=0;kp<128;kp++){
    unsigned ww=Wnp[(size_t)kp*256+tid];
    float lo=bfl(ww), hi=bfh(ww);
    #pragma unroll
    for(int row=0;row<16;row++){
      hw[row]+=h0sn[row*260+2*kp]*lo + h0sn[row*260+2*kp+1]*hi;
    }
  }
  #pragma unroll
  for(int row=0;row<16;row++){
    int grow=blk16+row;
    if(grow<NR2) HW[(size_t)grow*HD+tid]=hw[row];
  }
}

// Pipelined GEMM inner loop (unchanged)
template<int NK>
__device__ __forceinline__ void gemm_pipe(const char* smem, const v8s* __restrict__ Bf,
                                          int lane, int fr, int fg, int nf0, int kb0,
                                          v4f acc[2][8]){
  v8s bb0[8], bb1[8];
  #pragma unroll
  for(int n=0;n<8;n++) bb0[n]=Bf[(size_t)(kb0*32+nf0+n)*64+lane];
  #pragma unroll
  for(int i=0;i<NK;i++){
    if(i+1<NK){
      if((i&1)==0){
        #pragma unroll
        for(int n=0;n<8;n++) bb1[n]=Bf[(size_t)((kb0+i+1)*32+nf0+n)*64+lane];
      } else {
        #pragma unroll
        for(int n=0;n<8;n++) bb0[n]=Bf[(size_t)((kb0+i+1)*32+nf0+n)*64+lane];
      }
    }
    int k0=(kb0+i)*32;
    v8s af[2];
    #pragma unroll
    for(int m=0;m<2;m++){
      int row=m*16+fr;
      af[m]=*(const v8s*)(smem + (((row<<10)+k0*2+(fg<<4))^((row&7)<<4)));
    }
    #pragma unroll
    for(int m=0;m<2;m++){
      #pragma unroll
      for(int n=0;n<8;n++){
        acc[m][n]=__builtin_amdgcn_mfma_f32_16x16x32_bf16(af[m], ((i&1)?bb1:bb0)[n], acc[m][n],0,0,0);
      }
    }
  }
}

// D3: stage A + HW-gather (bf16 hwm) + MFMA GEMM + epilogue (r16 version)
__global__ __launch_bounds__(256,3) void k_fused(const unsigned short* __restrict__ Agg,
                                                 unsigned short* __restrict__ Hbf,
                                                 const v8s* __restrict__ Bfrag,
                                                 const float* __restrict__ HW,
                                                 const int* __restrict__ setype,
                                                 const int* __restrict__ offs,
                                                 const float* __restrict__ hprev,
                                                 float* __restrict__ outT){
  __shared__ __align__(16) char smem[49920];
  __shared__ float rsum[2][32];
  float* twl=(float*)smem;
  unsigned* hwm_u=(unsigned*)(smem+33024);
  int tid=threadIdx.x, lane=tid&63, wid=tid>>6;
  int fr=lane&15, fg=lane>>4;
  int m0=blockIdx.x*32;
  int iscur=(wid<2);
  int ncol0=wid*128;

  #pragma unroll
  for(int qq=0;qq<4;qq++){
    int cid=tid+qq*256;
    int row=cid>>5, ch=cid&31;
    int swz=(row&7)<<4;
    v8s av=*(const v8s*)(Agg + (size_t)(m0+row)*HD + ch*8);
    *(v8s*)(smem + (((row<<10)+(ch<<4))^swz)) = av;
    v8s hv=*(const v8s*)(Hbf + (size_t)(m0+row)*HD + ch*8);
    *(v8s*)(smem + (((row<<10)+512+(ch<<4))^swz)) = hv;
  }

  {
    int v=tid>>3, q=tid&7;
    int gv=m0+v;
    int s0=offs[gv], s1=offs[gv+1];
    v4f s[8]={};
    for(int e=s0;e<s1;e++){
      int et=setype[e];
      const float* hp=&HW[(size_t)et*HD];
      #pragma unroll
      for(int k=0;k<8;k++){
        v4f x=*(const v4f*)(hp + q*4 + k*32);
        s[k]+=x;
      }
    }
    float inv=1.f/fmaxf((float)(s1-s0),1.f);
    #pragma unroll
    for(int k=0;k<8;k++){
      uint2 p;
      p.x=pack2bf(s[k][0]*inv, s[k][1]*inv);
      p.y=pack2bf(s[k][2]*inv, s[k][3]*inv);
      *(uint2*)(hwm_u + v*132 + q*2 + k*16) = p;
    }
  }
  __syncthreads();

  v4f acc[2][8]={};
  if(iscur) gemm_pipe<16>(smem, Bfrag, lane, fr, fg, ncol0>>4, 0, acc);
  else      gemm_pipe<8> (smem, Bfrag, lane, fr, fg, ncol0>>4, 8, acc);
  __syncthreads();

  if(!iscur){
    #pragma unroll
    for(int m=0;m<2;m++){
      #pragma unroll
      for(int n=0;n<8;n++){
        int col=ncol0-256+n*16+fr;
        #pragma unroll
        for(int i=0;i<4;i++){
          int row=m*16+fg*4+i;
          twl[row*257+col]=sigmoidf_(acc[m][n][i]);
        }
      }
    }
  } else {
    #pragma unroll
    for(int m=0;m<2;m++){
      #pragma unroll
      for(int i=0;i<4;i++){
        int row=m*16+fg*4+i;
        float s=0.f;
        #pragma unroll
        for(int n=0;n<8;n++){
          int col=ncol0+n*16+fr;
          unsigned u=hwm_u[row*132 + (col>>1)];
          float hwv=(col&1)? bfh(u) : bfl(u);
          float c=acc[m][n][i] + hwv;
          c=(c>=0.f)? c : SLOPE*c;
          acc[m][n][i]=c;
          s+=c*c;
        }
        s+=__shfl_xor(s,1,64); s+=__shfl_xor(s,2,64);
        s+=__shfl_xor(s,4,64); s+=__shfl_xor(s,8,64);
        if(fr==0) rsum[wid][row]=s;
      }
    }
  }
  __syncthreads();

  if(iscur){
    #pragma unroll
    for(int m=0;m<2;m++){
      #pragma unroll
      for(int i=0;i<4;i++){
        int row=m*16+fg*4+i;
        float tot=rsum[0][row]+rsum[1][row];
        float inv=1.f/fmaxf(sqrtf(tot),1e-12f);
        #pragma unroll
        for(int n=0;n<8;n++){
          int col=ncol0+n*16+fr;
          float cn=acc[m][n][i]*inv;
          float tw=twl[row*257+col];
          float hp=hprev[(size_t)(m0+row)*HD+col];
          float o=tw*cn+(1.f-tw)*hp;
          outT[(size_t)(m0+row)*HD+col]=o;
          Hbf[(size_t)(m0+row)*HD+col]=f2bf(o);
        }
      }
    }
  }
}

// ---------------- launch ----------------

extern "C" void kernel_launch(void* const* d_in, const int* in_sizes, int n_in,
                              void* d_out, int out_size, void* d_ws, size_t ws_size,
                              hipStream_t stream) {
  const float* ent_emb   = (const float*)d_in[0];
  const float* emb_rel   = (const float*)d_in[1];
  const float* W_ih      = (const float*)d_in[2];
  const float* W_hh      = (const float*)d_in[3];
  const float* b_ih      = (const float*)d_in[4];
  const float* b_hh      = (const float*)d_in[5];
  const float* W_nb      = (const float*)d_in[6];
  const float* W_loop    = (const float*)d_in[7];
  const float* W_tg      = (const float*)d_in[8];
  const int*   r_to_e    = (const int*)d_in[10];
  const int*   r_rel     = (const int*)d_in[11];
  const int*   src       = (const int*)d_in[12];
  const int*   dst       = (const int*)d_in[13];
  const int*   etype     = (const int*)d_in[14];
  float* out = (float*)d_out;                       // (T,N,H)

  float* ws = (float*)d_ws;
  size_t off=0;
  auto alloc=[&](size_t n){ float* p=ws+off; off+=n; return p; };
  float* h_init  = alloc((size_t)NENT*HD);
  float* h0      = alloc((size_t)NR2P*HD);
  float* gi_const= alloc((size_t)NR2P*GDIM);
  float* WtA     = alloc((size_t)HD*GDIM);
  float* HW      = alloc((size_t)NR2P*HD);
  unsigned* WtBfr= (unsigned*)alloc(98304);
  unsigned* Whhfr= (unsigned*)alloc(98304);
  unsigned* Wnp  = (unsigned*)alloc((size_t)128*256);
  unsigned short* Hbf   = (unsigned short*)alloc((size_t)NENT*HD/2);
  unsigned short* h0bf  = (unsigned short*)alloc((size_t)NR2P*HD/2);
  unsigned* xmbf = (unsigned*)alloc((size_t)NR2P*128);
  unsigned short* aggbf = (unsigned short*)alloc((size_t)NENT*HD/2);
  unsigned* Bfrag = (unsigned*)alloc(131072);
  int* ib = (int*)(ws+off);
  int* deg    = ib;  ib += TT*NENT;
  int* offs   = ib;  ib += TT*(NENT+1);
  int* cursor = ib;  ib += TT*NENT;
  int* ssrc   = ib;  ib += TT*EE;
  int* setype = ib;  ib += TT*EE;

  const int TPB=256;

  // ---- setup (4 dispatches) ----
  k_l2norm_clear<<<NENT,TPB,0,stream>>>(ent_emb, h_init, Hbf, deg, cursor);
  k_prep<<<768,TPB,0,stream>>>(W_ih, W_hh, W_nb, W_loop, W_tg, emb_rel, dst,
                               WtA, WtBfr, Whhfr, Bfrag, Wnp, h0, h0bf, xmbf,
                               gi_const, deg);
  k_scangemm<<<TT+96,TPB,0,stream>>>(deg, offs, emb_rel, WtA, b_ih, gi_const);
  k_scatter8<<<(TT*EE+TPB-1)/TPB,TPB,0,stream>>>(dst, src, etype, offs, cursor, ssrc, setype);

  for(int t=0;t<TT;t++){
    const float* hprev = (t==0) ? h_init : out + (size_t)(t-1)*NENT*HD;

    k_gath<<<NR2+NAGG_BLK,TPB,0,stream>>>((const unsigned*)Hbf,
        ssrc + (size_t)t*EE, offs + (size_t)t*(NENT+1), (unsigned*)aggbf,
        r_to_e + (size_t)t*MM, r_rel + (size_t)t*MM, xmbf);
    k_gru<<<32,TPB,0,stream>>>(xmbf, WtBfr, Whhfr, Wnp, gi_const, b_hh,
        h0, h0bf, HW);
    k_fused<<<NENT/32,TPB,0,stream>>>(aggbf, Hbf, (const v8s*)Bfrag, HW,
        setype + (size_t)t*EE, offs + (size_t)t*(NENT+1),
        hprev, out + (size_t)t*NENT*HD);
  }
}

// Round 19
// 1410.402 us; speedup vs baseline: 1.0353x; 1.0353x over previous
//
#include <hip/hip_runtime.h>
#include <math.h>

#define NENT 20000
#define HD 256
#define TT 8
#define EE 100000
#define MM 150000
#define NR2 500
#define NR2P 512        /* padded rows */
#define GDIM 768
#define SLOPE 0.2291666666666667f
#define NAGG_BLK 2500

typedef short v8s __attribute__((ext_vector_type(8)));
typedef float v4f __attribute__((ext_vector_type(4)));

__device__ __forceinline__ float sigmoidf_(float x){ return 1.0f/(1.0f+expf(-x)); }
__device__ __forceinline__ unsigned short f2bf(float x){
  unsigned u = __float_as_uint(x);
  return (unsigned short)((u + 0x7FFFu + ((u>>16)&1u)) >> 16);
}
__device__ __forceinline__ unsigned pack2bf(float lo, float hi){
  return ((unsigned)f2bf(lo)) | (((unsigned)f2bf(hi))<<16);
}
__device__ __forceinline__ float bfl(unsigned u){ return __uint_as_float(u<<16); }
__device__ __forceinline__ float bfh(unsigned u){ return __uint_as_float(u & 0xffff0000u); }

__device__ __forceinline__ float block_sum_256(float v){
  #pragma unroll
  for(int o=32;o>0;o>>=1) v += __shfl_down(v,o,64);
  __shared__ float wsum[4];
  __shared__ float tot;
  int lane = threadIdx.x & 63, wid = threadIdx.x >> 6;
  if(lane==0) wsum[wid]=v;
  __syncthreads();
  if(threadIdx.x==0) tot = wsum[0]+wsum[1]+wsum[2]+wsum[3];
  __syncthreads();
  return tot;
}

// ---------------- setup kernels ----------------

__global__ __launch_bounds__(256) void k_l2norm_clear(const float* __restrict__ in,
                                                      float* __restrict__ out,
                                                      unsigned short* __restrict__ outbf,
                                                      int* __restrict__ deg,
                                                      int* __restrict__ cursor){
  int r=blockIdx.x, j=threadIdx.x;
  size_t idx=(size_t)r*HD+j;
  float v = in[idx];
  float ss = block_sum_256(v*v);
  float o = v / fmaxf(sqrtf(ss), 1e-12f);
  out[idx] = o;
  outbf[idx] = f2bf(o);
  for(int i=blockIdx.x*256+threadIdx.x; i<TT*NENT; i+=gridDim.x*256){
    deg[i]=0; cursor[i]=0;
  }
}

// weight prep + degree count + pad-zeroing.
__global__ __launch_bounds__(256) void k_prep(const float* __restrict__ W_ih,
                                              const float* __restrict__ W_hh,
                                              const float* __restrict__ Wn,
                                              const float* __restrict__ Wl,
                                              const float* __restrict__ Wtg,
                                              const float* __restrict__ emb_rel,
                                              const int* __restrict__ dst,
                                              float* __restrict__ WtA,
                                              unsigned* __restrict__ WtBfr,
                                              unsigned* __restrict__ Whhfr,
                                              unsigned* __restrict__ Bfrag_u,
                                              unsigned* __restrict__ Wnp,
                                              float* __restrict__ h0,
                                              unsigned short* __restrict__ h0bf,
                                              unsigned* __restrict__ xmbf,
                                              float* __restrict__ gi_const_pad,
                                              int* __restrict__ deg){
  int id0=blockIdx.x*256+threadIdx.x;
  int stride=gridDim.x*256;
  for(int id=id0; id<256*GDIM; id+=stride){
    int k=id/GDIM, n=id%GDIM;
    WtA[id]=W_ih[(size_t)n*512+k];
  }
  for(int id=id0; id<98304; id+=stride){
    int vidx=id>>2, j=id&3;
    int lane=vidx&63;
    int f=(vidx>>6)%48;
    int kblk=vidx/(48*64);           // 0..7 (K=256)
    int n=f*16+(lane&15);
    int k=kblk*32+(lane>>4)*8+2*j;
    WtBfr[id]=pack2bf(W_ih[(size_t)n*512+256+k], W_ih[(size_t)n*512+256+k+1]);
    Whhfr[id]=pack2bf(W_hh[(size_t)n*256+k],     W_hh[(size_t)n*256+k+1]);
  }
  for(int id=id0; id<131072; id+=stride){
    int vidx = id>>2, j = id&3;
    int lane = vidx&63, frag = (vidx>>6)&31, kblk = vidx>>11;
    int nr = frag*16 + (lane&15);
    int k  = kblk*32 + (lane>>4)*8 + 2*j;
    float lo, hi;
    if(nr < HD){
      lo = (k<HD)?     Wn[(size_t)k*HD+nr]      : Wl[(size_t)(k-HD)*HD+nr];
      hi = (k+1<HD)?   Wn[(size_t)(k+1)*HD+nr]  : Wl[(size_t)(k+1-HD)*HD+nr];
    } else {
      lo = (k<HD)?   0.f : Wtg[(size_t)(k-HD)*HD+(nr-HD)];
      hi = (k+1<HD)? 0.f : Wtg[(size_t)(k+1-HD)*HD+(nr-HD)];
    }
    Bfrag_u[id]=pack2bf(lo,hi);
  }
  for(int id=id0; id<128*256; id+=stride){
    int kp=id>>8, col=id&255;
    Wnp[id]=pack2bf(Wn[(size_t)(2*kp)*HD+col], Wn[(size_t)(2*kp+1)*HD+col]);
  }
  for(int id=id0; id<NR2*HD; id+=stride){ h0[id]=emb_rel[id]; h0bf[id]=f2bf(emb_rel[id]); }
  for(int id=id0; id<12*HD; id+=stride){ h0[NR2*HD+id]=0.f; h0bf[NR2*HD+id]=0; }
  for(int id=id0; id<12*128; id+=stride) xmbf[NR2*128+id]=0;
  for(int id=id0; id<12*GDIM; id+=stride) gi_const_pad[(size_t)NR2*GDIM+id]=0.f;
  for(int id=id0; id<TT*EE; id+=stride){
    int t=id/EE, e=id-t*EE;
    atomicAdd(&deg[t*NENT + dst[(size_t)t*EE+e]], 1);
  }
}

// role-split: blocks [0,TT) per-timestep scan; blocks [TT,TT+96) gi_const GEMM
__global__ __launch_bounds__(256) void k_scangemm(const int* __restrict__ deg_all,
                                                  int* __restrict__ offs_all,
                                                  const float* __restrict__ A,
                                                  const float* __restrict__ B,
                                                  const float* __restrict__ bias,
                                                  float* __restrict__ C){
  int tid=threadIdx.x;
  if(blockIdx.x < TT){
    int t=blockIdx.x;
    const int* deg=deg_all+t*NENT;
    int* offs=offs_all+t*(NENT+1);
    __shared__ int part[256];
    const int per=(NENT+255)>>8;
    int base=tid*per;
    int s=0;
    for(int i=0;i<per;i++){ int idx=base+i; if(idx<NENT) s+=deg[idx]; }
    part[tid]=s;
    __syncthreads();
    for(int off=1; off<256; off<<=1){
      int v=(tid>=off)? part[tid-off]:0;
      __syncthreads();
      part[tid]+=v;
      __syncthreads();
    }
    int run=part[tid]-s;
    for(int i=0;i<per;i++){ int idx=base+i; if(idx<NENT){ offs[idx]=run; run+=deg[idx]; } }
    if(tid==255) offs[NENT]=part[255];
    return;
  }
  int tile=blockIdx.x-TT;
  int n0=(tile%12)*64, m0=(tile/12)*64;
  __shared__ float As[16][64];
  __shared__ float Bs[16][64];
  int tx=tid&15, ty=tid>>4;
  float acc[4][4]={};
  for(int k0=0;k0<HD;k0+=16){
    int ml=tid>>2, kl=(tid&3)*4;
    float4 av=make_float4(0.f,0.f,0.f,0.f);
    if(m0+ml<NR2) av=*(const float4*)&A[(size_t)(m0+ml)*HD+k0+kl];
    As[kl+0][ml]=av.x; As[kl+1][ml]=av.y; As[kl+2][ml]=av.z; As[kl+3][ml]=av.w;
    int kb=tid>>4, nb=(tid&15)*4;
    float4 bv=*(const float4*)&B[(size_t)(k0+kb)*GDIM+n0+nb];
    *(float4*)&Bs[kb][nb]=bv;
    __syncthreads();
    #pragma unroll
    for(int kk=0;kk<16;kk++){
      float a0=As[kk][ty*4+0],a1=As[kk][ty*4+1],a2=As[kk][ty*4+2],a3=As[kk][ty*4+3];
      float b0=Bs[kk][tx*4+0],b1=Bs[kk][tx*4+1],b2=Bs[kk][tx*4+2],b3=Bs[kk][tx*4+3];
      acc[0][0]+=a0*b0; acc[0][1]+=a0*b1; acc[0][2]+=a0*b2; acc[0][3]+=a0*b3;
      acc[1][0]+=a1*b0; acc[1][1]+=a1*b1; acc[1][2]+=a1*b2; acc[1][3]+=a1*b3;
      acc[2][0]+=a2*b0; acc[2][1]+=a2*b1; acc[2][2]+=a2*b2; acc[2][3]+=a2*b3;
      acc[3][0]+=a3*b0; acc[3][1]+=a3*b1; acc[3][2]+=a3*b2; acc[3][3]+=a3*b3;
    }
    __syncthreads();
  }
  #pragma unroll
  for(int i=0;i<4;i++){
    int row=m0+ty*4+i;
    if(row>=NR2) continue;
    #pragma unroll
    for(int j=0;j<4;j++){
      int col=n0+tx*4+j;
      C[(size_t)row*GDIM+col]=acc[i][j]+bias[col];
    }
  }
}

__global__ __launch_bounds__(256) void k_scatter8(const int* __restrict__ dst,
                                                  const int* __restrict__ src,
                                                  const int* __restrict__ et,
                                                  const int* __restrict__ offs_all,
                                                  int* __restrict__ cursor,
                                                  int* __restrict__ ssrc,
                                                  int* __restrict__ setype){
  int id=blockIdx.x*256+threadIdx.x;
  if(id>=TT*EE) return;
  int t=id/EE, e=id-t*EE;
  size_t ge=(size_t)t*EE+e;
  int d=dst[ge];
  int p = offs_all[t*(NENT+1)+d] + atomicAdd(&cursor[t*NENT+d], 1);
  ssrc[(size_t)t*EE+p]=src[ge];
  setype[(size_t)t*EE+p]=et[ge];
}

// ---------------- per-step kernels ----------------

// D1: pure gathers. blocks [0,NR2): xmean -> xmbf (bf16); [NR2,NR2+NAGG_BLK): srcagg.
__global__ __launch_bounds__(256) void k_gath(
    const unsigned* __restrict__ Hbf_u,
    const int* __restrict__ ssrc,
    const int* __restrict__ offs,
    unsigned* __restrict__ aggsrc,
    const int* __restrict__ rte, const int* __restrict__ rrel,
    unsigned* __restrict__ xmbf)
{
  int bid=blockIdx.x, tid=threadIdx.x;
  int lane=tid&63, wid=tid>>6;

  if(bid >= NR2){
    int gw=(bid-NR2)*4+wid;
    const int nw=NAGG_BLK*4;
    for(int v=gw; v<NENT; v+=nw){
      int s0=offs[v], s1=offs[v+1];
      float l0=0.f,g0=0.f,l1=0.f,g1=0.f;
      float m0=0.f,n0=0.f,m1=0.f,n1=0.f;
      int e=s0;
      for(; e+1<s1; e+=2){
        int sv1=ssrc[e], sv2=ssrc[e+1];
        uint2 w1=*(const uint2*)&Hbf_u[(size_t)sv1*128 + 2*lane];
        uint2 w2=*(const uint2*)&Hbf_u[(size_t)sv2*128 + 2*lane];
        l0+=bfl(w1.x); g0+=bfh(w1.x);
        l1+=bfl(w1.y); g1+=bfh(w1.y);
        m0+=bfl(w2.x); n0+=bfh(w2.x);
        m1+=bfl(w2.y); n1+=bfh(w2.y);
      }
      if(e<s1){
        int sv=ssrc[e];
        uint2 w1=*(const uint2*)&Hbf_u[(size_t)sv*128 + 2*lane];
        l0+=bfl(w1.x); g0+=bfh(w1.x);
        l1+=bfl(w1.y); g1+=bfh(w1.y);
      }
      l0+=m0; g0+=n0; l1+=m1; g1+=n1;
      float inv=1.f/fmaxf((float)(s1-s0),1.f);
      uint2 o;
      o.x=pack2bf(l0*inv,g0*inv);
      o.y=pack2bf(l1*inv,g1*inv);
      *(uint2*)&aggsrc[(size_t)v*128 + 2*lane]=o;
    }
    return;
  }

  // ---- xmean for relation r ----
  int r=bid;
  __shared__ int buf[64];
  __shared__ float comb[128][2];
  int lo=0, hi=MM;
  while(lo<hi){ int mid=(lo+hi)>>1; if(rrel[mid]<r) lo=mid+1; else hi=mid; }
  int start=lo;
  lo=start; hi=MM;
  while(lo<hi){ int mid=(lo+hi)>>1; if(rrel[mid]<r+1) lo=mid+1; else hi=mid; }
  int end=lo;

  int half = tid>>7, cp = tid&127;
  float a0=0.f,a1=0.f,b0=0.f,b1=0.f;
  float c0=0.f,c1=0.f,d0=0.f,d1=0.f;
  for(int q0=start; q0<end; q0+=64){
    int cnt = min(64, end-q0);
    __syncthreads();
    if(tid<cnt) buf[tid]=rte[q0+tid];
    __syncthreads();
    int i = half;
    for(; i+6<cnt; i+=8){
      unsigned u1 = Hbf_u[(size_t)buf[i]*128 + cp];
      unsigned u2 = Hbf_u[(size_t)buf[i+2]*128 + cp];
      unsigned u3 = Hbf_u[(size_t)buf[i+4]*128 + cp];
      unsigned u4 = Hbf_u[(size_t)buf[i+6]*128 + cp];
      a0 += bfl(u1); a1 += bfh(u1);
      b0 += bfl(u2); b1 += bfh(u2);
      c0 += bfl(u3); c1 += bfh(u3);
      d0 += bfl(u4); d1 += bfh(u4);
    }
    for(; i<cnt; i+=2){
      unsigned u1 = Hbf_u[(size_t)buf[i]*128 + cp];
      a0 += bfl(u1); a1 += bfh(u1);
    }
  }
  a0+=b0+c0+d0; a1+=b1+c1+d1;
  if(half==1){ comb[cp][0]=a0; comb[cp][1]=a1; }
  __syncthreads();
  if(half==0){
    float d = fmaxf((float)(end-start), 1.f);
    xmbf[(size_t)r*128+cp]=pack2bf((a0+comb[cp][0])/d, (a1+comb[cp][1])/d);
  }
}

// D2: GRU via MFMA (K=256 -> 8 kblks). 32 blocks x 16 rows.
// __launch_bounds__(256,1): allow up to 512 VGPR so all 24 B-fragments of a
// kblk can be in flight (r18's 128-VGPR cap serialized every load -> 126 us).
__global__ __launch_bounds__(256,1) void k_gru(
    const unsigned* __restrict__ xmbf,
    const unsigned* __restrict__ WtBfr,
    const unsigned* __restrict__ Whhfr,
    const unsigned* __restrict__ Wnp,
    const float* __restrict__ gic,
    const float* __restrict__ b_hh,
    float* h0,                     // rw
    unsigned short* h0bf,          // rw
    float* __restrict__ HW)
{
  __shared__ __align__(16) char smem[33280];
  float* h0sn=(float*)(smem+16384);
  float (*rsum)[16]=(float(*)[16])(smem+33024);
  int tid=threadIdx.x, lane=tid&63, w=tid>>6;
  int fr=lane&15, fg=lane>>4;
  int blk16=blockIdx.x*16;

  const unsigned* h0bf_u=(const unsigned*)h0bf;
  #pragma unroll
  for(int q=0;q<8;q++){
    int idx=tid+q*256;
    int row=idx>>7, cu=idx&127;
    unsigned xv=xmbf[(size_t)(blk16+row)*128+cu];
    unsigned hv=h0bf_u[(size_t)(blk16+row)*128+cu];
    int byte=(row*512+cu*4)^((row&7)<<4);
    *(unsigned*)(smem+byte)=xv;
    *(unsigned*)(smem+8192+byte)=hv;
  }
  #pragma unroll
  for(int q=0;q<16;q++){
    int idx=tid+q*256;
    int row=idx>>8, c=idx&255;
    h0sn[row*260+c]=h0[(size_t)(blk16+row)*HD+c];
  }
  __syncthreads();

  // GEMMs over K=256 (8 kblks); all 24 B-frags of a kblk loaded before MFMAs
  v4f agi[12]={}, agh[12]={};
  #pragma unroll
  for(int kblk=0;kblk<8;kblk++){
    int abyte=(fr*512 + kblk*64 + fg*16)^((fr&7)<<4);
    v8s afx=*(const v8s*)(smem+abyte);
    v8s afh=*(const v8s*)(smem+8192+abyte);
    v8s bx[12], bh[12];
    #pragma unroll
    for(int q=0;q<12;q++){
      int f=(q>>2)*16 + 4*w + (q&3);
      bx[q]=*(const v8s*)&WtBfr[((size_t)(kblk*48+f)*64+lane)*4];
      bh[q]=*(const v8s*)&Whhfr[((size_t)(kblk*48+f)*64+lane)*4];
    }
    #pragma unroll
    for(int q=0;q<12;q++){
      agi[q]=__builtin_amdgcn_mfma_f32_16x16x32_bf16(afx,bx[q],agi[q],0,0,0);
      agh[q]=__builtin_amdgcn_mfma_f32_16x16x32_bf16(afh,bh[q],agh[q],0,0,0);
    }
  }

  // gates + l2norm
  float hn[4][4];
  float ssum[4]={};
  #pragma unroll
  for(int j=0;j<4;j++){
    int c=(4*w+j)*16+fr;
    #pragma unroll
    for(int i=0;i<4;i++){
      int row16=fg*4+i;
      size_t gb=(size_t)(blk16+row16)*GDIM;
      float ir=agi[0+j][i]+gic[gb+c];
      float iz=agi[4+j][i]+gic[gb+256+c];
      float ig=agi[8+j][i]+gic[gb+512+c];
      float hr=agh[0+j][i]+b_hh[c];
      float hz=agh[4+j][i]+b_hh[256+c];
      float hg=agh[8+j][i]+b_hh[512+c];
      float rr=sigmoidf_(ir+hr), z=sigmoidf_(iz+hz);
      float g=tanhf(ig+rr*hg);
      float v=(1.f-z)*g + z*h0sn[row16*260+c];
      hn[j][i]=v;
      ssum[i]+=v*v;
    }
  }
  #pragma unroll
  for(int i=0;i<4;i++){
    float s=ssum[i];
    s+=__shfl_xor(s,1,64); s+=__shfl_xor(s,2,64);
    s+=__shfl_xor(s,4,64); s+=__shfl_xor(s,8,64);
    if(fr==0) rsum[w][fg*4+i]=s;
  }
  __syncthreads();
  #pragma unroll
  for(int i=0;i<4;i++){
    int row16=fg*4+i;
    int grow=blk16+row16;
    float tot=rsum[0][row16]+rsum[1][row16]+rsum[2][row16]+rsum[3][row16];
    float inv=1.f/fmaxf(sqrtf(tot),1e-12f);
    #pragma unroll
    for(int j=0;j<4;j++){
      int c=(4*w+j)*16+fr;
      float o=hn[j][i]*inv;
      h0sn[row16*260+c]=o;
      if(grow<NR2){
        h0[(size_t)grow*HD+c]=o;
        h0bf[(size_t)grow*HD+c]=f2bf(o);
      }
    }
  }
  __syncthreads();

  // HW = h0_new @ Wn
  float hw[16]={};
  #pragma unroll 8
  for(int kp=0;kp<128;kp++){
    unsigned ww=Wnp[(size_t)kp*256+tid];
    float lo=bfl(ww), hi=bfh(ww);
    #pragma unroll
    for(int row=0;row<16;row++){
      hw[row]+=h0sn[row*260+2*kp]*lo + h0sn[row*260+2*kp+1]*hi;
    }
  }
  #pragma unroll
  for(int row=0;row<16;row++){
    int grow=blk16+row;
    if(grow<NR2) HW[(size_t)grow*HD+tid]=hw[row];
  }
}

// Pipelined GEMM inner loop (unchanged)
template<int NK>
__device__ __forceinline__ void gemm_pipe(const char* smem, const v8s* __restrict__ Bf,
                                          int lane, int fr, int fg, int nf0, int kb0,
                                          v4f acc[2][8]){
  v8s bb0[8], bb1[8];
  #pragma unroll
  for(int n=0;n<8;n++) bb0[n]=Bf[(size_t)(kb0*32+nf0+n)*64+lane];
  #pragma unroll
  for(int i=0;i<NK;i++){
    if(i+1<NK){
      if((i&1)==0){
        #pragma unroll
        for(int n=0;n<8;n++) bb1[n]=Bf[(size_t)((kb0+i+1)*32+nf0+n)*64+lane];
      } else {
        #pragma unroll
        for(int n=0;n<8;n++) bb0[n]=Bf[(size_t)((kb0+i+1)*32+nf0+n)*64+lane];
      }
    }
    int k0=(kb0+i)*32;
    v8s af[2];
    #pragma unroll
    for(int m=0;m<2;m++){
      int row=m*16+fr;
      af[m]=*(const v8s*)(smem + (((row<<10)+k0*2+(fg<<4))^((row&7)<<4)));
    }
    #pragma unroll
    for(int m=0;m<2;m++){
      #pragma unroll
      for(int n=0;n<8;n++){
        acc[m][n]=__builtin_amdgcn_mfma_f32_16x16x32_bf16(af[m], ((i&1)?bb1:bb0)[n], acc[m][n],0,0,0);
      }
    }
  }
}

// D3: stage A + HW-gather (bf16 hwm) + MFMA GEMM + epilogue
__global__ __launch_bounds__(256,3) void k_fused(const unsigned short* __restrict__ Agg,
                                                 unsigned short* __restrict__ Hbf,
                                                 const v8s* __restrict__ Bfrag,
                                                 const float* __restrict__ HW,
                                                 const int* __restrict__ setype,
                                                 const int* __restrict__ offs,
                                                 const float* __restrict__ hprev,
                                                 float* __restrict__ outT){
  __shared__ __align__(16) char smem[49920];
  __shared__ float rsum[2][32];
  float* twl=(float*)smem;
  unsigned* hwm_u=(unsigned*)(smem+33024);
  int tid=threadIdx.x, lane=tid&63, wid=tid>>6;
  int fr=lane&15, fg=lane>>4;
  int m0=blockIdx.x*32;
  int iscur=(wid<2);
  int ncol0=wid*128;

  #pragma unroll
  for(int qq=0;qq<4;qq++){
    int cid=tid+qq*256;
    int row=cid>>5, ch=cid&31;
    int swz=(row&7)<<4;
    v8s av=*(const v8s*)(Agg + (size_t)(m0+row)*HD + ch*8);
    *(v8s*)(smem + (((row<<10)+(ch<<4))^swz)) = av;
    v8s hv=*(const v8s*)(Hbf + (size_t)(m0+row)*HD + ch*8);
    *(v8s*)(smem + (((row<<10)+512+(ch<<4))^swz)) = hv;
  }

  {
    int v=tid>>3, q=tid&7;
    int gv=m0+v;
    int s0=offs[gv], s1=offs[gv+1];
    v4f s[8]={};
    for(int e=s0;e<s1;e++){
      int et=setype[e];
      const float* hp=&HW[(size_t)et*HD];
      #pragma unroll
      for(int k=0;k<8;k++){
        v4f x=*(const v4f*)(hp + q*4 + k*32);
        s[k]+=x;
      }
    }
    float inv=1.f/fmaxf((float)(s1-s0),1.f);
    #pragma unroll
    for(int k=0;k<8;k++){
      uint2 p;
      p.x=pack2bf(s[k][0]*inv, s[k][1]*inv);
      p.y=pack2bf(s[k][2]*inv, s[k][3]*inv);
      *(uint2*)(hwm_u + v*132 + q*2 + k*16) = p;
    }
  }
  __syncthreads();

  v4f acc[2][8]={};
  if(iscur) gemm_pipe<16>(smem, Bfrag, lane, fr, fg, ncol0>>4, 0, acc);
  else      gemm_pipe<8> (smem, Bfrag, lane, fr, fg, ncol0>>4, 8, acc);
  __syncthreads();

  if(!iscur){
    #pragma unroll
    for(int m=0;m<2;m++){
      #pragma unroll
      for(int n=0;n<8;n++){
        int col=ncol0-256+n*16+fr;
        #pragma unroll
        for(int i=0;i<4;i++){
          int row=m*16+fg*4+i;
          twl[row*257+col]=sigmoidf_(acc[m][n][i]);
        }
      }
    }
  } else {
    #pragma unroll
    for(int m=0;m<2;m++){
      #pragma unroll
      for(int i=0;i<4;i++){
        int row=m*16+fg*4+i;
        float s=0.f;
        #pragma unroll
        for(int n=0;n<8;n++){
          int col=ncol0+n*16+fr;
          unsigned u=hwm_u[row*132 + (col>>1)];
          float hwv=(col&1)? bfh(u) : bfl(u);
          float c=acc[m][n][i] + hwv;
          c=(c>=0.f)? c : SLOPE*c;
          acc[m][n][i]=c;
          s+=c*c;
        }
        s+=__shfl_xor(s,1,64); s+=__shfl_xor(s,2,64);
        s+=__shfl_xor(s,4,64); s+=__shfl_xor(s,8,64);
        if(fr==0) rsum[wid][row]=s;
      }
    }
  }
  __syncthreads();

  if(iscur){
    #pragma unroll
    for(int m=0;m<2;m++){
      #pragma unroll
      for(int i=0;i<4;i++){
        int row=m*16+fg*4+i;
        float tot=rsum[0][row]+rsum[1][row];
        float inv=1.f/fmaxf(sqrtf(tot),1e-12f);
        #pragma unroll
        for(int n=0;n<8;n++){
          int col=ncol0+n*16+fr;
          float cn=acc[m][n][i]*inv;
          float tw=twl[row*257+col];
          float hp=hprev[(size_t)(m0+row)*HD+col];
          float o=tw*cn+(1.f-tw)*hp;
          outT[(size_t)(m0+row)*HD+col]=o;
          Hbf[(size_t)(m0+row)*HD+col]=f2bf(o);
        }
      }
    }
  }
}

// ---------------- launch ----------------

extern "C" void kernel_launch(void* const* d_in, const int* in_sizes, int n_in,
                              void* d_out, int out_size, void* d_ws, size_t ws_size,
                              hipStream_t stream) {
  const float* ent_emb   = (const float*)d_in[0];
  const float* emb_rel   = (const float*)d_in[1];
  const float* W_ih      = (const float*)d_in[2];
  const float* W_hh      = (const float*)d_in[3];
  const float* b_ih      = (const float*)d_in[4];
  const float* b_hh      = (const float*)d_in[5];
  const float* W_nb      = (const float*)d_in[6];
  const float* W_loop    = (const float*)d_in[7];
  const float* W_tg      = (const float*)d_in[8];
  const int*   r_to_e    = (const int*)d_in[10];
  const int*   r_rel     = (const int*)d_in[11];
  const int*   src       = (const int*)d_in[12];
  const int*   dst       = (const int*)d_in[13];
  const int*   etype     = (const int*)d_in[14];
  float* out = (float*)d_out;                       // (T,N,H)

  float* ws = (float*)d_ws;
  size_t off=0;
  auto alloc=[&](size_t n){ float* p=ws+off; off+=n; return p; };
  float* h_init  = alloc((size_t)NENT*HD);
  float* h0      = alloc((size_t)NR2P*HD);
  float* gi_const= alloc((size_t)NR2P*GDIM);
  float* WtA     = alloc((size_t)HD*GDIM);
  float* HW      = alloc((size_t)NR2P*HD);
  unsigned* WtBfr= (unsigned*)alloc(98304);
  unsigned* Whhfr= (unsigned*)alloc(98304);
  unsigned* Wnp  = (unsigned*)alloc((size_t)128*256);
  unsigned short* Hbf   = (unsigned short*)alloc((size_t)NENT*HD/2);
  unsigned short* h0bf  = (unsigned short*)alloc((size_t)NR2P*HD/2);
  unsigned* xmbf = (unsigned*)alloc((size_t)NR2P*128);
  unsigned short* aggbf = (unsigned short*)alloc((size_t)NENT*HD/2);
  unsigned* Bfrag = (unsigned*)alloc(131072);
  int* ib = (int*)(ws+off);
  int* deg    = ib;  ib += TT*NENT;
  int* offs   = ib;  ib += TT*(NENT+1);
  int* cursor = ib;  ib += TT*NENT;
  int* ssrc   = ib;  ib += TT*EE;
  int* setype = ib;  ib += TT*EE;

  const int TPB=256;

  // ---- setup (4 dispatches) ----
  k_l2norm_clear<<<NENT,TPB,0,stream>>>(ent_emb, h_init, Hbf, deg, cursor);
  k_prep<<<768,TPB,0,stream>>>(W_ih, W_hh, W_nb, W_loop, W_tg, emb_rel, dst,
                               WtA, WtBfr, Whhfr, Bfrag, Wnp, h0, h0bf, xmbf,
                               gi_const, deg);
  k_scangemm<<<TT+96,TPB,0,stream>>>(deg, offs, emb_rel, WtA, b_ih, gi_const);
  k_scatter8<<<(TT*EE+TPB-1)/TPB,TPB,0,stream>>>(dst, src, etype, offs, cursor, ssrc, setype);

  for(int t=0;t<TT;t++){
    const float* hprev = (t==0) ? h_init : out + (size_t)(t-1)*NENT*HD;

    k_gath<<<NR2+NAGG_BLK,TPB,0,stream>>>((const unsigned*)Hbf,
        ssrc + (size_t)t*EE, offs + (size_t)t*(NENT+1), (unsigned*)aggbf,
        r_to_e + (size_t)t*MM, r_rel + (size_t)t*MM, xmbf);
    k_gru<<<32,TPB,0,stream>>>(xmbf, WtBfr, Whhfr, Wnp, gi_const, b_hh,
        h0, h0bf, HW);
    k_fused<<<NENT/32,TPB,0,stream>>>(aggbf, Hbf, (const v8s*)Bfrag, HW,
        setype + (size_t)t*EE, offs + (size_t)t*(NENT+1),
        hprev, out + (size_t)t*NENT*HD);
  }
}

// Round 20
// 742.390 us; speedup vs baseline: 1.9668x; 1.8998x over previous
//
#include <hip/hip_runtime.h>
#include <math.h>

#define NENT 20000
#define HD 256
#define TT 8
#define EE 100000
#define MM 150000
#define NR2 500
#define NR2P 512        /* padded rows */
#define GDIM 768
#define SLOPE 0.2291666666666667f
#define NAGG_BLK 2500

typedef short v8s __attribute__((ext_vector_type(8)));
typedef float v4f __attribute__((ext_vector_type(4)));

__device__ __forceinline__ float sigmoidf_(float x){ return 1.0f/(1.0f+expf(-x)); }
__device__ __forceinline__ unsigned short f2bf(float x){
  unsigned u = __float_as_uint(x);
  return (unsigned short)((u + 0x7FFFu + ((u>>16)&1u)) >> 16);
}
__device__ __forceinline__ unsigned pack2bf(float lo, float hi){
  return ((unsigned)f2bf(lo)) | (((unsigned)f2bf(hi))<<16);
}
__device__ __forceinline__ float bfl(unsigned u){ return __uint_as_float(u<<16); }
__device__ __forceinline__ float bfh(unsigned u){ return __uint_as_float(u & 0xffff0000u); }

__device__ __forceinline__ float block_sum_256(float v){
  #pragma unroll
  for(int o=32;o>0;o>>=1) v += __shfl_down(v,o,64);
  __shared__ float wsum[4];
  __shared__ float tot;
  int lane = threadIdx.x & 63, wid = threadIdx.x >> 6;
  if(lane==0) wsum[wid]=v;
  __syncthreads();
  if(threadIdx.x==0) tot = wsum[0]+wsum[1]+wsum[2]+wsum[3];
  __syncthreads();
  return tot;
}

// ---------------- setup kernels ----------------

__global__ __launch_bounds__(256) void k_l2norm_clear(const float* __restrict__ in,
                                                      float* __restrict__ out,
                                                      unsigned short* __restrict__ outbf,
                                                      int* __restrict__ deg,
                                                      int* __restrict__ cursor){
  int r=blockIdx.x, j=threadIdx.x;
  size_t idx=(size_t)r*HD+j;
  float v = in[idx];
  float ss = block_sum_256(v*v);
  float o = v / fmaxf(sqrtf(ss), 1e-12f);
  out[idx] = o;
  outbf[idx] = f2bf(o);
  for(int i=blockIdx.x*256+threadIdx.x; i<TT*NENT; i+=gridDim.x*256){
    deg[i]=0; cursor[i]=0;
  }
}

// weight prep + degree count + pad-zeroing.
__global__ __launch_bounds__(256) void k_prep(const float* __restrict__ W_ih,
                                              const float* __restrict__ W_hh,
                                              const float* __restrict__ Wn,
                                              const float* __restrict__ Wl,
                                              const float* __restrict__ Wtg,
                                              const float* __restrict__ emb_rel,
                                              const int* __restrict__ dst,
                                              float* __restrict__ WtA,
                                              unsigned* __restrict__ WtBfr,
                                              unsigned* __restrict__ Whhfr,
                                              unsigned* __restrict__ Bfrag_u,
                                              float* __restrict__ h0,
                                              unsigned short* __restrict__ h0bf,
                                              unsigned* __restrict__ xmbf,
                                              float* __restrict__ gi_const_pad,
                                              int* __restrict__ deg){
  int id0=blockIdx.x*256+threadIdx.x;
  int stride=gridDim.x*256;
  for(int id=id0; id<256*GDIM; id+=stride){
    int k=id/GDIM, n=id%GDIM;
    WtA[id]=W_ih[(size_t)n*512+k];
  }
  for(int id=id0; id<98304; id+=stride){
    int vidx=id>>2, j=id&3;
    int lane=vidx&63;
    int f=(vidx>>6)%48;
    int kblk=vidx/(48*64);           // 0..7 (K=256)
    int n=f*16+(lane&15);
    int k=kblk*32+(lane>>4)*8+2*j;
    WtBfr[id]=pack2bf(W_ih[(size_t)n*512+256+k], W_ih[(size_t)n*512+256+k+1]);
    Whhfr[id]=pack2bf(W_hh[(size_t)n*256+k],     W_hh[(size_t)n*256+k+1]);
  }
  for(int id=id0; id<131072; id+=stride){
    int vidx = id>>2, j = id&3;
    int lane = vidx&63, frag = (vidx>>6)&31, kblk = vidx>>11;
    int nr = frag*16 + (lane&15);
    int k  = kblk*32 + (lane>>4)*8 + 2*j;
    float lo, hi;
    if(nr < HD){
      lo = (k<HD)?     Wn[(size_t)k*HD+nr]      : Wl[(size_t)(k-HD)*HD+nr];
      hi = (k+1<HD)?   Wn[(size_t)(k+1)*HD+nr]  : Wl[(size_t)(k+1-HD)*HD+nr];
    } else {
      lo = (k<HD)?   0.f : Wtg[(size_t)(k-HD)*HD+(nr-HD)];
      hi = (k+1<HD)? 0.f : Wtg[(size_t)(k+1-HD)*HD+(nr-HD)];
    }
    Bfrag_u[id]=pack2bf(lo,hi);
  }
  for(int id=id0; id<NR2*HD; id+=stride){ h0[id]=emb_rel[id]; h0bf[id]=f2bf(emb_rel[id]); }
  for(int id=id0; id<12*HD; id+=stride){ h0[NR2*HD+id]=0.f; h0bf[NR2*HD+id]=0; }
  for(int id=id0; id<12*128; id+=stride) xmbf[NR2*128+id]=0;
  for(int id=id0; id<12*GDIM; id+=stride) gi_const_pad[(size_t)NR2*GDIM+id]=0.f;
  for(int id=id0; id<TT*EE; id+=stride){
    int t=id/EE, e=id-t*EE;
    atomicAdd(&deg[t*NENT + dst[(size_t)t*EE+e]], 1);
  }
}

// role-split: blocks [0,TT) per-timestep scan; blocks [TT,TT+96) gi_const GEMM
__global__ __launch_bounds__(256) void k_scangemm(const int* __restrict__ deg_all,
                                                  int* __restrict__ offs_all,
                                                  const float* __restrict__ A,
                                                  const float* __restrict__ B,
                                                  const float* __restrict__ bias,
                                                  float* __restrict__ C){
  int tid=threadIdx.x;
  if(blockIdx.x < TT){
    int t=blockIdx.x;
    const int* deg=deg_all+t*NENT;
    int* offs=offs_all+t*(NENT+1);
    __shared__ int part[256];
    const int per=(NENT+255)>>8;
    int base=tid*per;
    int s=0;
    for(int i=0;i<per;i++){ int idx=base+i; if(idx<NENT) s+=deg[idx]; }
    part[tid]=s;
    __syncthreads();
    for(int off=1; off<256; off<<=1){
      int v=(tid>=off)? part[tid-off]:0;
      __syncthreads();
      part[tid]+=v;
      __syncthreads();
    }
    int run=part[tid]-s;
    for(int i=0;i<per;i++){ int idx=base+i; if(idx<NENT){ offs[idx]=run; run+=deg[idx]; } }
    if(tid==255) offs[NENT]=part[255];
    return;
  }
  int tile=blockIdx.x-TT;
  int n0=(tile%12)*64, m0=(tile/12)*64;
  __shared__ float As[16][64];
  __shared__ float Bs[16][64];
  int tx=tid&15, ty=tid>>4;
  float acc[4][4]={};
  for(int k0=0;k0<HD;k0+=16){
    int ml=tid>>2, kl=(tid&3)*4;
    float4 av=make_float4(0.f,0.f,0.f,0.f);
    if(m0+ml<NR2) av=*(const float4*)&A[(size_t)(m0+ml)*HD+k0+kl];
    As[kl+0][ml]=av.x; As[kl+1][ml]=av.y; As[kl+2][ml]=av.z; As[kl+3][ml]=av.w;
    int kb=tid>>4, nb=(tid&15)*4;
    float4 bv=*(const float4*)&B[(size_t)(k0+kb)*GDIM+n0+nb];
    *(float4*)&Bs[kb][nb]=bv;
    __syncthreads();
    #pragma unroll
    for(int kk=0;kk<16;kk++){
      float a0=As[kk][ty*4+0],a1=As[kk][ty*4+1],a2=As[kk][ty*4+2],a3=As[kk][ty*4+3];
      float b0=Bs[kk][tx*4+0],b1=Bs[kk][tx*4+1],b2=Bs[kk][tx*4+2],b3=Bs[kk][tx*4+3];
      acc[0][0]+=a0*b0; acc[0][1]+=a0*b1; acc[0][2]+=a0*b2; acc[0][3]+=a0*b3;
      acc[1][0]+=a1*b0; acc[1][1]+=a1*b1; acc[1][2]+=a1*b2; acc[1][3]+=a1*b3;
      acc[2][0]+=a2*b0; acc[2][1]+=a2*b1; acc[2][2]+=a2*b2; acc[2][3]+=a2*b3;
      acc[3][0]+=a3*b0; acc[3][1]+=a3*b1; acc[3][2]+=a3*b2; acc[3][3]+=a3*b3;
    }
    __syncthreads();
  }
  #pragma unroll
  for(int i=0;i<4;i++){
    int row=m0+ty*4+i;
    if(row>=NR2) continue;
    #pragma unroll
    for(int j=0;j<4;j++){
      int col=n0+tx*4+j;
      C[(size_t)row*GDIM+col]=acc[i][j]+bias[col];
    }
  }
}

__global__ __launch_bounds__(256) void k_scatter8(const int* __restrict__ dst,
                                                  const int* __restrict__ src,
                                                  const int* __restrict__ et,
                                                  const int* __restrict__ offs_all,
                                                  int* __restrict__ cursor,
                                                  int* __restrict__ ssrc,
                                                  int* __restrict__ setype){
  int id=blockIdx.x*256+threadIdx.x;
  if(id>=TT*EE) return;
  int t=id/EE, e=id-t*EE;
  size_t ge=(size_t)t*EE+e;
  int d=dst[ge];
  int p = offs_all[t*(NENT+1)+d] + atomicAdd(&cursor[t*NENT+d], 1);
  ssrc[(size_t)t*EE+p]=src[ge];
  setype[(size_t)t*EE+p]=et[ge];
}

// ---------------- per-step kernels ----------------

// D1: pure gathers. blocks [0,NR2): xmean -> xmbf (bf16); [NR2,NR2+NAGG_BLK): srcagg.
__global__ __launch_bounds__(256) void k_gath(
    const unsigned* __restrict__ Hbf_u,
    const int* __restrict__ ssrc,
    const int* __restrict__ offs,
    unsigned* __restrict__ aggsrc,
    const int* __restrict__ rte, const int* __restrict__ rrel,
    unsigned* __restrict__ xmbf)
{
  int bid=blockIdx.x, tid=threadIdx.x;
  int lane=tid&63, wid=tid>>6;

  if(bid >= NR2){
    int gw=(bid-NR2)*4+wid;
    const int nw=NAGG_BLK*4;
    for(int v=gw; v<NENT; v+=nw){
      int s0=offs[v], s1=offs[v+1];
      float l0=0.f,g0=0.f,l1=0.f,g1=0.f;
      float m0=0.f,n0=0.f,m1=0.f,n1=0.f;
      int e=s0;
      for(; e+1<s1; e+=2){
        int sv1=ssrc[e], sv2=ssrc[e+1];
        uint2 w1=*(const uint2*)&Hbf_u[(size_t)sv1*128 + 2*lane];
        uint2 w2=*(const uint2*)&Hbf_u[(size_t)sv2*128 + 2*lane];
        l0+=bfl(w1.x); g0+=bfh(w1.x);
        l1+=bfl(w1.y); g1+=bfh(w1.y);
        m0+=bfl(w2.x); n0+=bfh(w2.x);
        m1+=bfl(w2.y); n1+=bfh(w2.y);
      }
      if(e<s1){
        int sv=ssrc[e];
        uint2 w1=*(const uint2*)&Hbf_u[(size_t)sv*128 + 2*lane];
        l0+=bfl(w1.x); g0+=bfh(w1.x);
        l1+=bfl(w1.y); g1+=bfh(w1.y);
      }
      l0+=m0; g0+=n0; l1+=m1; g1+=n1;
      float inv=1.f/fmaxf((float)(s1-s0),1.f);
      uint2 o;
      o.x=pack2bf(l0*inv,g0*inv);
      o.y=pack2bf(l1*inv,g1*inv);
      *(uint2*)&aggsrc[(size_t)v*128 + 2*lane]=o;
    }
    return;
  }

  // ---- xmean for relation r ----
  int r=bid;
  __shared__ int buf[64];
  __shared__ float comb[128][2];
  int lo=0, hi=MM;
  while(lo<hi){ int mid=(lo+hi)>>1; if(rrel[mid]<r) lo=mid+1; else hi=mid; }
  int start=lo;
  lo=start; hi=MM;
  while(lo<hi){ int mid=(lo+hi)>>1; if(rrel[mid]<r+1) lo=mid+1; else hi=mid; }
  int end=lo;

  int half = tid>>7, cp = tid&127;
  float a0=0.f,a1=0.f,b0=0.f,b1=0.f;
  float c0=0.f,c1=0.f,d0=0.f,d1=0.f;
  for(int q0=start; q0<end; q0+=64){
    int cnt = min(64, end-q0);
    __syncthreads();
    if(tid<cnt) buf[tid]=rte[q0+tid];
    __syncthreads();
    int i = half;
    for(; i+6<cnt; i+=8){
      unsigned u1 = Hbf_u[(size_t)buf[i]*128 + cp];
      unsigned u2 = Hbf_u[(size_t)buf[i+2]*128 + cp];
      unsigned u3 = Hbf_u[(size_t)buf[i+4]*128 + cp];
      unsigned u4 = Hbf_u[(size_t)buf[i+6]*128 + cp];
      a0 += bfl(u1); a1 += bfh(u1);
      b0 += bfl(u2); b1 += bfh(u2);
      c0 += bfl(u3); c1 += bfh(u3);
      d0 += bfl(u4); d1 += bfh(u4);
    }
    for(; i<cnt; i+=2){
      unsigned u1 = Hbf_u[(size_t)buf[i]*128 + cp];
      a0 += bfl(u1); a1 += bfh(u1);
    }
  }
  a0+=b0+c0+d0; a1+=b1+c1+d1;
  if(half==1){ comb[cp][0]=a0; comb[cp][1]=a1; }
  __syncthreads();
  if(half==0){
    float d = fmaxf((float)(end-start), 1.f);
    xmbf[(size_t)r*128+cp]=pack2bf((a0+comb[cp][0])/d, (a1+comb[cp][1])/d);
  }
}

// D2: GRU via MFMA (K=256 -> 8 kblks). 32 blocks x 1024 threads (16 waves).
// Wave w owns frag-triple w: cols c=w*16+fr, gates at c, c+256, c+512.
// Per kblk per wave: 6 B-frag loads + 6 MFMAs (light regs -> loads pipeline).
// LDS: xma bf16 [16][256] swz @0 (8KB) | h0a swz @8192 (8KB)
//      h0s f32 [16][260] @16384 | rsum[16][16] @33024
__global__ __launch_bounds__(1024) void k_gru(
    const unsigned* __restrict__ xmbf,
    const unsigned* __restrict__ WtBfr,
    const unsigned* __restrict__ Whhfr,
    const float* __restrict__ gic,
    const float* __restrict__ b_hh,
    float* h0,                     // rw
    unsigned short* h0bf)          // rw
{
  __shared__ __align__(16) char smem[34048];
  float* h0s=(float*)(smem+16384);                 // [16][260]
  float (*rsum)[16]=(float(*)[16])(smem+33024);    // [w][row]
  int tid=threadIdx.x, lane=tid&63, w=tid>>6;      // w 0..15
  int fr=lane&15, fg=lane>>4;
  int blk16=blockIdx.x*16;

  const unsigned* h0bf_u=(const unsigned*)h0bf;
  #pragma unroll
  for(int q=0;q<2;q++){
    int idx=tid+q*1024;
    int row=idx>>7, cu=idx&127;
    unsigned xv=xmbf[(size_t)(blk16+row)*128+cu];
    unsigned hv=h0bf_u[(size_t)(blk16+row)*128+cu];
    int byte=(row*512+cu*4)^((row&7)<<4);
    *(unsigned*)(smem+byte)=xv;
    *(unsigned*)(smem+8192+byte)=hv;
  }
  #pragma unroll
  for(int q=0;q<4;q++){
    int idx=tid+q*1024;
    int row=idx>>8, c=idx&255;
    h0s[row*260+c]=h0[(size_t)(blk16+row)*HD+c];
  }
  __syncthreads();

  // GEMMs over K=256: wave's 3 gi-frags + 3 gh-frags per kblk
  v4f agi[3]={}, agh[3]={};
  #pragma unroll
  for(int kblk=0;kblk<8;kblk++){
    int abyte=(fr*512 + kblk*64 + fg*16)^((fr&7)<<4);
    v8s afx=*(const v8s*)(smem+abyte);
    v8s afh=*(const v8s*)(smem+8192+abyte);
    v8s bx[3], bh[3];
    #pragma unroll
    for(int g=0;g<3;g++){
      int f=g*16+w;
      bx[g]=*(const v8s*)&WtBfr[((size_t)(kblk*48+f)*64+lane)*4];
      bh[g]=*(const v8s*)&Whhfr[((size_t)(kblk*48+f)*64+lane)*4];
    }
    #pragma unroll
    for(int g=0;g<3;g++){
      agi[g]=__builtin_amdgcn_mfma_f32_16x16x32_bf16(afx,bx[g],agi[g],0,0,0);
      agh[g]=__builtin_amdgcn_mfma_f32_16x16x32_bf16(afh,bh[g],agh[g],0,0,0);
    }
  }

  // gates + per-wave partial row sums
  int c=w*16+fr;
  float hn[4];
  {
    float bh0=b_hh[c], bh1=b_hh[256+c], bh2=b_hh[512+c];
    #pragma unroll
    for(int i=0;i<4;i++){
      int row16=fg*4+i;
      size_t gb=(size_t)(blk16+row16)*GDIM;
      float ir=agi[0][i]+gic[gb+c];
      float iz=agi[1][i]+gic[gb+256+c];
      float ig=agi[2][i]+gic[gb+512+c];
      float hr=agh[0][i]+bh0;
      float hz=agh[1][i]+bh1;
      float hg=agh[2][i]+bh2;
      float rr=sigmoidf_(ir+hr), z=sigmoidf_(iz+hz);
      float g=tanhf(ig+rr*hg);
      float v=(1.f-z)*g + z*h0s[row16*260+c];
      hn[i]=v;
      float s=v*v;
      s+=__shfl_xor(s,1,64); s+=__shfl_xor(s,2,64);
      s+=__shfl_xor(s,4,64); s+=__shfl_xor(s,8,64);
      if(fr==0) rsum[w][row16]=s;
    }
  }
  __syncthreads();
  #pragma unroll
  for(int i=0;i<4;i++){
    int row16=fg*4+i;
    int grow=blk16+row16;
    float tot=0.f;
    #pragma unroll
    for(int ww=0;ww<16;ww++) tot+=rsum[ww][row16];
    float inv=1.f/fmaxf(sqrtf(tot),1e-12f);
    float o=hn[i]*inv;
    if(grow<NR2){
      h0[(size_t)grow*HD+c]=o;
      h0bf[(size_t)grow*HD+c]=f2bf(o);
    }
  }
}

// Pipelined GEMM inner loop (unchanged)
template<int NK>
__device__ __forceinline__ void gemm_pipe(const char* smem, const v8s* __restrict__ Bf,
                                          int lane, int fr, int fg, int nf0, int kb0,
                                          v4f acc[2][8]){
  v8s bb0[8], bb1[8];
  #pragma unroll
  for(int n=0;n<8;n++) bb0[n]=Bf[(size_t)(kb0*32+nf0+n)*64+lane];
  #pragma unroll
  for(int i=0;i<NK;i++){
    if(i+1<NK){
      if((i&1)==0){
        #pragma unroll
        for(int n=0;n<8;n++) bb1[n]=Bf[(size_t)((kb0+i+1)*32+nf0+n)*64+lane];
      } else {
        #pragma unroll
        for(int n=0;n<8;n++) bb0[n]=Bf[(size_t)((kb0+i+1)*32+nf0+n)*64+lane];
      }
    }
    int k0=(kb0+i)*32;
    v8s af[2];
    #pragma unroll
    for(int m=0;m<2;m++){
      int row=m*16+fr;
      af[m]=*(const v8s*)(smem + (((row<<10)+k0*2+(fg<<4))^((row&7)<<4)));
    }
    #pragma unroll
    for(int m=0;m<2;m++){
      #pragma unroll
      for(int n=0;n<8;n++){
        acc[m][n]=__builtin_amdgcn_mfma_f32_16x16x32_bf16(af[m], ((i&1)?bb1:bb0)[n], acc[m][n],0,0,0);
      }
    }
  }
}

// D3: A-tile = (srcmean + h0bf-mean) for k<256, Hbf for k>=256; then GEMM + epilogue.
__global__ __launch_bounds__(256,3) void k_fused(const unsigned* __restrict__ aggsrc_u,
                                                 unsigned short* __restrict__ Hbf,
                                                 const v8s* __restrict__ Bfrag,
                                                 const unsigned* __restrict__ h0bf_u,
                                                 const int* __restrict__ setype,
                                                 const int* __restrict__ offs,
                                                 const float* __restrict__ hprev,
                                                 float* __restrict__ outT){
  __shared__ __align__(16) char smem[33024];
  __shared__ float rsum[2][32];
  float* twl=(float*)smem;
  int tid=threadIdx.x, lane=tid&63, wid=tid>>6;
  int fr=lane&15, fg=lane>>4;
  int m0=blockIdx.x*32;
  int iscur=(wid<2);
  int ncol0=wid*128;

  // ---- Hbf staging (k 256-511) ----
  #pragma unroll
  for(int qq=0;qq<4;qq++){
    int cid=tid+qq*256;
    int row=cid>>5, ch=cid&31;
    int swz=(row&7)<<4;
    v8s hv=*(const v8s*)(Hbf + (size_t)(m0+row)*HD + ch*8);
    *(v8s*)(smem + (((row<<10)+512+(ch<<4))^swz)) = hv;
  }

  // ---- h0bf-mean gather + combine with srcmean -> A-tile k<256 ----
  {
    int v=tid>>3, q=tid&7;          // v 0..31, q 0..7 (cols q*32..+31)
    int gv=m0+v;
    int s0=offs[gv], s1=offs[gv+1];
    float s[32]={};
    for(int e=s0;e<s1;e++){
      int et=setype[e];
      const uint4* hp=(const uint4*)(h0bf_u + (size_t)et*128 + q*16);
      #pragma unroll
      for(int k4=0;k4<4;k4++){
        uint4 x=hp[k4];
        s[k4*8+0]+=bfl(x.x); s[k4*8+1]+=bfh(x.x);
        s[k4*8+2]+=bfl(x.y); s[k4*8+3]+=bfh(x.y);
        s[k4*8+4]+=bfl(x.z); s[k4*8+5]+=bfh(x.z);
        s[k4*8+6]+=bfl(x.w); s[k4*8+7]+=bfh(x.w);
      }
    }
    float inv=1.f/fmaxf((float)(s1-s0),1.f);
    #pragma unroll
    for(int c4=0;c4<4;c4++){
      uint4 a=*(const uint4*)(aggsrc_u + (size_t)gv*128 + q*16 + c4*4);
      uint4 rr;
      rr.x=pack2bf(bfl(a.x)+s[c4*8+0]*inv, bfh(a.x)+s[c4*8+1]*inv);
      rr.y=pack2bf(bfl(a.y)+s[c4*8+2]*inv, bfh(a.y)+s[c4*8+3]*inv);
      rr.z=pack2bf(bfl(a.z)+s[c4*8+4]*inv, bfh(a.z)+s[c4*8+5]*inv);
      rr.w=pack2bf(bfl(a.w)+s[c4*8+6]*inv, bfh(a.w)+s[c4*8+7]*inv);
      int byte=((v<<10) + q*64 + c4*16)^((v&7)<<4);
      *(uint4*)(smem+byte)=rr;
    }
  }
  __syncthreads();

  v4f acc[2][8]={};
  if(iscur) gemm_pipe<16>(smem, Bfrag, lane, fr, fg, ncol0>>4, 0, acc);
  else      gemm_pipe<8> (smem, Bfrag, lane, fr, fg, ncol0>>4, 8, acc);
  __syncthreads();   // A reads done; twl may overwrite

  if(!iscur){
    #pragma unroll
    for(int m=0;m<2;m++){
      #pragma unroll
      for(int n=0;n<8;n++){
        int col=ncol0-256+n*16+fr;
        #pragma unroll
        for(int i=0;i<4;i++){
          int row=m*16+fg*4+i;
          twl[row*257+col]=sigmoidf_(acc[m][n][i]);
        }
      }
    }
  } else {
    #pragma unroll
    for(int m=0;m<2;m++){
      #pragma unroll
      for(int i=0;i<4;i++){
        int row=m*16+fg*4+i;
        float s=0.f;
        #pragma unroll
        for(int n=0;n<8;n++){
          float cc=acc[m][n][i];
          cc=(cc>=0.f)? cc : SLOPE*cc;
          acc[m][n][i]=cc;
          s+=cc*cc;
        }
        s+=__shfl_xor(s,1,64); s+=__shfl_xor(s,2,64);
        s+=__shfl_xor(s,4,64); s+=__shfl_xor(s,8,64);
        if(fr==0) rsum[wid][row]=s;
      }
    }
  }
  __syncthreads();

  if(iscur){
    #pragma unroll
    for(int m=0;m<2;m++){
      #pragma unroll
      for(int i=0;i<4;i++){
        int row=m*16+fg*4+i;
        float tot=rsum[0][row]+rsum[1][row];
        float inv=1.f/fmaxf(sqrtf(tot),1e-12f);
        #pragma unroll
        for(int n=0;n<8;n++){
          int col=ncol0+n*16+fr;
          float cn=acc[m][n][i]*inv;
          float tw=twl[row*257+col];
          float hp=hprev[(size_t)(m0+row)*HD+col];
          float o=tw*cn+(1.f-tw)*hp;
          outT[(size_t)(m0+row)*HD+col]=o;
          Hbf[(size_t)(m0+row)*HD+col]=f2bf(o);
        }
      }
    }
  }
}

// ---------------- launch ----------------

extern "C" void kernel_launch(void* const* d_in, const int* in_sizes, int n_in,
                              void* d_out, int out_size, void* d_ws, size_t ws_size,
                              hipStream_t stream) {
  const float* ent_emb   = (const float*)d_in[0];
  const float* emb_rel   = (const float*)d_in[1];
  const float* W_ih      = (const float*)d_in[2];
  const float* W_hh      = (const float*)d_in[3];
  const float* b_ih      = (const float*)d_in[4];
  const float* b_hh      = (const float*)d_in[5];
  const float* W_nb      = (const float*)d_in[6];
  const float* W_loop    = (const float*)d_in[7];
  const float* W_tg      = (const float*)d_in[8];
  const int*   r_to_e    = (const int*)d_in[10];
  const int*   r_rel     = (const int*)d_in[11];
  const int*   src       = (const int*)d_in[12];
  const int*   dst       = (const int*)d_in[13];
  const int*   etype     = (const int*)d_in[14];
  float* out = (float*)d_out;                       // (T,N,H)

  float* ws = (float*)d_ws;
  size_t off=0;
  auto alloc=[&](size_t n){ float* p=ws+off; off+=n; return p; };
  float* h_init  = alloc((size_t)NENT*HD);
  float* h0      = alloc((size_t)NR2P*HD);
  float* gi_const= alloc((size_t)NR2P*GDIM);
  float* WtA     = alloc((size_t)HD*GDIM);
  unsigned* WtBfr= (unsigned*)alloc(98304);
  unsigned* Whhfr= (unsigned*)alloc(98304);
  unsigned short* Hbf   = (unsigned short*)alloc((size_t)NENT*HD/2);
  unsigned short* h0bf  = (unsigned short*)alloc((size_t)NR2P*HD/2);
  unsigned* xmbf = (unsigned*)alloc((size_t)NR2P*128);
  unsigned short* aggbf = (unsigned short*)alloc((size_t)NENT*HD/2);
  unsigned* Bfrag = (unsigned*)alloc(131072);
  int* ib = (int*)(ws+off);
  int* deg    = ib;  ib += TT*NENT;
  int* offs   = ib;  ib += TT*(NENT+1);
  int* cursor = ib;  ib += TT*NENT;
  int* ssrc   = ib;  ib += TT*EE;
  int* setype = ib;  ib += TT*EE;

  const int TPB=256;

  // ---- setup (4 dispatches) ----
  k_l2norm_clear<<<NENT,TPB,0,stream>>>(ent_emb, h_init, Hbf, deg, cursor);
  k_prep<<<768,TPB,0,stream>>>(W_ih, W_hh, W_nb, W_loop, W_tg, emb_rel, dst,
                               WtA, WtBfr, Whhfr, Bfrag, h0, h0bf, xmbf,
                               gi_const, deg);
  k_scangemm<<<TT+96,TPB,0,stream>>>(deg, offs, emb_rel, WtA, b_ih, gi_const);
  k_scatter8<<<(TT*EE+TPB-1)/TPB,TPB,0,stream>>>(dst, src, etype, offs, cursor, ssrc, setype);

  for(int t=0;t<TT;t++){
    const float* hprev = (t==0) ? h_init : out + (size_t)(t-1)*NENT*HD;

    k_gath<<<NR2+NAGG_BLK,TPB,0,stream>>>((const unsigned*)Hbf,
        ssrc + (size_t)t*EE, offs + (size_t)t*(NENT+1), (unsigned*)aggbf,
        r_to_e + (size_t)t*MM, r_rel + (size_t)t*MM, xmbf);
    k_gru<<<32,1024,0,stream>>>(xmbf, WtBfr, Whhfr, gi_const, b_hh, h0, h0bf);
    k_fused<<<NENT/32,TPB,0,stream>>>((const unsigned*)aggbf, Hbf,
        (const v8s*)Bfrag, (const unsigned*)h0bf,
        setype + (size_t)t*EE, offs + (size_t)t*(NENT+1),
        hprev, out + (size_t)t*NENT*HD);
  }
}